// Round 2
// baseline (200.300 us; speedup 1.0000x reference)
//
#include <hip/hip_runtime.h>

// x (N,D,L) f32, weight (K,D) f32, scale (1,) f32
// out (N,K,L) f32 = (||x||^2 + ||c||^2 - 2 x.c) / scale^2
#define N_ 32
#define D_ 128
#define L_ 3136
#define K_ 64
#define NQ 4           // K-split: waves per block (threadIdx.y)
#define KT (K_ / NQ)   // 16 accumulators per thread -> ~45 VGPRs, no spill

// Block = (64 columns) x (4 k-quarters) = 256 threads = 4 waves.
// q = threadIdx.y is wave-uniform -> weight rows come in as scalar loads.
// All 4 waves read the same x column chunks -> L1 hits after the first wave.
// Grid = (3136/64, 32) = (49, 32) -> 6272 waves, ~24.5 waves/CU.
__global__ __launch_bounds__(256, 6) void enc_dist_kernel(
    const float* __restrict__ x,
    const float* __restrict__ w,
    const float* __restrict__ scale,
    float* __restrict__ out)
{
    const int tx = threadIdx.x;   // 0..63: column lane
    const int q  = threadIdx.y;   // 0..3:  k-quarter (wave-uniform)
    const int n  = blockIdx.y;
    const int l  = blockIdx.x * 64 + tx;

    // ---- ||c_k||^2 into LDS, one row per thread (first 64 linear threads) ----
    __shared__ float c_sq[K_];
    const int lin = q * 64 + tx;
    if (lin < K_) {
        const float* wr = w + (size_t)lin * D_;
        float s = 0.f;
#pragma unroll
        for (int d = 0; d < D_; d += 4) {
            float4 wv = *(const float4*)(wr + d);
            s = fmaf(wv.x, wv.x, s);
            s = fmaf(wv.y, wv.y, s);
            s = fmaf(wv.z, wv.z, s);
            s = fmaf(wv.w, wv.w, s);
        }
        c_sq[lin] = s;
    }
    __syncthreads();

    // ---- main loop: acc[k] = sum_d x[n,d,l]*w[q*KT+k,d], software-pipelined ----
    const float* xp = x + (size_t)n * D_ * L_ + l;
    const float* wq = w + (size_t)(q * KT) * D_;

    float acc[KT];
#pragma unroll
    for (int k = 0; k < KT; ++k) acc[k] = 0.f;
    float x_sq = 0.f;

    float cur[8], nxt[8];
#pragma unroll
    for (int i = 0; i < 8; ++i) cur[i] = xp[(size_t)i * L_];

    for (int d0 = 0; d0 < D_ - 8; d0 += 8) {
        // prefetch next 8 x values while doing 16x8 FMAs on current chunk
#pragma unroll
        for (int i = 0; i < 8; ++i) nxt[i] = xp[(size_t)(d0 + 8 + i) * L_];
#pragma unroll
        for (int i = 0; i < 8; ++i) x_sq = fmaf(cur[i], cur[i], x_sq);
#pragma unroll
        for (int k = 0; k < KT; ++k) {
            float a = acc[k];
            const float* wr = wq + (size_t)k * D_ + d0;  // wave-uniform -> s_load
#pragma unroll
            for (int i = 0; i < 8; ++i) a = fmaf(cur[i], wr[i], a);
            acc[k] = a;
        }
#pragma unroll
        for (int i = 0; i < 8; ++i) cur[i] = nxt[i];
    }
    {   // last chunk (d0 = D_-8), no prefetch
        const int d0 = D_ - 8;
#pragma unroll
        for (int i = 0; i < 8; ++i) x_sq = fmaf(cur[i], cur[i], x_sq);
#pragma unroll
        for (int k = 0; k < KT; ++k) {
            float a = acc[k];
            const float* wr = wq + (size_t)k * D_ + d0;
#pragma unroll
            for (int i = 0; i < 8; ++i) a = fmaf(cur[i], wr[i], a);
            acc[k] = a;
        }
    }

    // ---- epilogue: fuse terms, scale, coalesced stores ----
    const float sc = scale[0];
    const float inv_s2 = 1.0f / (sc * sc);
    float* op = out + (size_t)n * K_ * L_ + (size_t)(q * KT) * L_ + l;
#pragma unroll
    for (int k = 0; k < KT; ++k) {
        op[(size_t)k * L_] = (x_sq + c_sq[q * KT + k] - 2.0f * acc[k]) * inv_s2;
    }
}

extern "C" void kernel_launch(void* const* d_in, const int* in_sizes, int n_in,
                              void* d_out, int out_size, void* d_ws, size_t ws_size,
                              hipStream_t stream) {
    const float* x     = (const float*)d_in[0];
    const float* w     = (const float*)d_in[1];
    const float* scale = (const float*)d_in[2];
    float* out = (float*)d_out;

    dim3 grid(L_ / 64, N_);     // (49, 32), no tail (49*64 = 3136)
    dim3 block(64, NQ);         // 256 threads = 4 waves
    enc_dist_kernel<<<grid, block, 0, stream>>>(x, w, scale, out);
}

// Round 3
// 123.542 us; speedup vs baseline: 1.6213x; 1.6213x over previous
//
#include <hip/hip_runtime.h>

// x (N,D,L) f32, weight (K,D) f32, scale (1,) f32
// out (N,K,L) f32 = (||x||^2 + ||c||^2 - 2 x.c) / scale^2
#define N_ 32
#define D_ 128
#define L_ 3136
#define K_ 64
#define NQ 4           // K-split across blockIdx.z (NOT threadIdx -> keeps weight loads scalar)
#define KT (K_ / NQ)   // 16 accumulators per thread

// Block = 64 threads (1 wave), one output column (n,l) x 16 codebook rows.
// Weight addresses depend only on SGPRs (blockIdx.z) + constants -> s_load
// (scalar pipe, parallel to VALU). x loads: 8 coalesced dwords per iter,
// double-buffered. Grid = (49, 32, 4) = 6272 waves ~ 6 waves/SIMD.
__global__ __launch_bounds__(64, 8) void enc_dist_kernel(
    const float* __restrict__ x,
    const float* __restrict__ w,
    const float* __restrict__ scale,
    float* __restrict__ out)
{
    const int tid = threadIdx.x;     // 0..63: column lane
    const int n   = blockIdx.y;      // 0..31
    const int kq  = blockIdx.z;      // 0..3: k-quarter (SGPR -> scalar weight addrs)
    const int l   = blockIdx.x * 64 + tid;

    // ---- ||c_k||^2 for this block's 16 rows -> LDS ----
    __shared__ float c_sq[KT];
    if (tid < KT) {
        const float* wr = w + (size_t)(kq * KT + tid) * D_;
        float s = 0.f;
#pragma unroll
        for (int d = 0; d < D_; d += 4) {
            float4 wv = *(const float4*)(wr + d);
            s = fmaf(wv.x, wv.x, s);
            s = fmaf(wv.y, wv.y, s);
            s = fmaf(wv.z, wv.z, s);
            s = fmaf(wv.w, wv.w, s);
        }
        c_sq[tid] = s;
    }
    __syncthreads();

    // ---- main loop: acc[k] = sum_d x[n,d,l] * w[kq*KT+k, d] ----
    const float* xp = x + (size_t)n * D_ * L_ + l;
    const float* wq = w + (size_t)kq * KT * D_;   // uniform base

    float acc[KT];
#pragma unroll
    for (int k = 0; k < KT; ++k) acc[k] = 0.f;
    float x_sq = 0.f;

    float cur[8], nxt[8];
#pragma unroll
    for (int i = 0; i < 8; ++i) cur[i] = xp[(size_t)i * L_];

    for (int d0 = 0; d0 < D_ - 8; d0 += 8) {
        // prefetch next x chunk while computing on current
#pragma unroll
        for (int i = 0; i < 8; ++i) nxt[i] = xp[(size_t)(d0 + 8 + i) * L_];
#pragma unroll
        for (int i = 0; i < 8; ++i) x_sq = fmaf(cur[i], cur[i], x_sq);
#pragma unroll
        for (int k = 0; k < KT; ++k) {
            float a = acc[k];
            const float* wr = wq + (size_t)k * D_ + d0;  // uniform -> s_load
#pragma unroll
            for (int i = 0; i < 8; ++i) a = fmaf(cur[i], wr[i], a);
            acc[k] = a;
        }
#pragma unroll
        for (int i = 0; i < 8; ++i) cur[i] = nxt[i];
    }
    {   // last chunk (d0 = D_-8)
        const int d0 = D_ - 8;
#pragma unroll
        for (int i = 0; i < 8; ++i) x_sq = fmaf(cur[i], cur[i], x_sq);
#pragma unroll
        for (int k = 0; k < KT; ++k) {
            float a = acc[k];
            const float* wr = wq + (size_t)k * D_ + d0;
#pragma unroll
            for (int i = 0; i < 8; ++i) a = fmaf(cur[i], wr[i], a);
            acc[k] = a;
        }
    }

    // ---- epilogue: fuse terms, scale, coalesced stores ----
    const float sc = scale[0];
    const float inv_s2 = 1.0f / (sc * sc);
    float* op = out + (size_t)n * K_ * L_ + (size_t)kq * KT * L_ + l;
#pragma unroll
    for (int k = 0; k < KT; ++k) {
        op[(size_t)k * L_] = (x_sq + c_sq[k] - 2.0f * acc[k]) * inv_s2;
    }
}

extern "C" void kernel_launch(void* const* d_in, const int* in_sizes, int n_in,
                              void* d_out, int out_size, void* d_ws, size_t ws_size,
                              hipStream_t stream) {
    const float* x     = (const float*)d_in[0];
    const float* w     = (const float*)d_in[1];
    const float* scale = (const float*)d_in[2];
    float* out = (float*)d_out;

    dim3 grid(L_ / 64, N_, NQ);   // (49, 32, 4), no tail (49*64 = 3136)
    enc_dist_kernel<<<grid, 64, 0, stream>>>(x, w, scale, out);
}

// Round 4
// 100.836 us; speedup vs baseline: 1.9864x; 1.2252x over previous
//
#include <hip/hip_runtime.h>

// x (N,D,L) f32, weight (K,D) f32, scale (1,) f32
// out (N,K,L) f32 = (||x||^2 + ||c||^2 - 2 x.c) / scale^2
#define N_ 32
#define D_ 128
#define L_ 3136
#define K_ 64
#define WSTR 136   // padded W row stride in bf16 elems: 272 B, 16B-aligned, bank-balanced b128

typedef short bf16x8 __attribute__((ext_vector_type(8)));
typedef float f32x4  __attribute__((ext_vector_type(4)));

__device__ inline unsigned short f2bf(float f) {       // RNE fp32->bf16 (finite data)
    unsigned u = __float_as_uint(f);
    return (unsigned short)((u + 0x7FFFu + ((u >> 16) & 1u)) >> 16);
}
__device__ inline float bf2f(unsigned short h) {
    return __uint_as_float(((unsigned)h) << 16);
}

// Block: 256 thr = 4 waves. Tile: 64 l x 64 k x one n, full D=128 contraction.
// Split-bf16 (hi/lo) 3-term MFMA => fp32-level accuracy at matrix-core speed.
__global__ __launch_bounds__(256, 4) void enc_mfma_kernel(
    const float* __restrict__ x,
    const float* __restrict__ w,
    const float* __restrict__ scale,
    float* __restrict__ out)
{
    __shared__ __attribute__((aligned(16))) unsigned short lds_wl[K_ * WSTR];
    __shared__ __attribute__((aligned(16))) char lds_u[K_ * WSTR * 2]; // W-hi, reused as C-tile
    __shared__ float lds_csqp[4][64];
    __shared__ float lds_csq[K_];
    __shared__ float lds_xsq[64];

    unsigned short* lds_wh = (unsigned short*)lds_u;
    float* lds_c = (float*)lds_u;   // 64 x 65 f32 = 16640 B <= 17408 B (fits W-hi region)

    const int t    = threadIdx.x;   // 0..255
    const int wave = t >> 6;
    const int lane = t & 63;
    const int col  = lane & 15;     // MFMA free-dim lane index
    const int quad = lane >> 4;

    const int n  = blockIdx.y;
    const int l0 = blockIdx.x * 64;

    // ---- stage W -> bf16 hi/lo in LDS; ||c_k||^2 partials on the side ----
    {
        const int k = t & 63, q = t >> 6;        // row k, d-quarter q
        const float* wr = w + (size_t)k * D_ + q * 32;
        float s = 0.f;
        for (int j = 0; j < 32; j += 4) {
            float4 v = *(const float4*)(wr + j);
            float vv[4] = {v.x, v.y, v.z, v.w};
            __attribute__((aligned(8))) unsigned short hbuf[4], lbuf[4];
#pragma unroll
            for (int c = 0; c < 4; ++c) {
                s = fmaf(vv[c], vv[c], s);
                unsigned short h = f2bf(vv[c]);
                hbuf[c] = h;
                lbuf[c] = f2bf(vv[c] - bf2f(h));
            }
            const int off = k * WSTR + q * 32 + j;
            *(ushort4*)&lds_wh[off] = *(const ushort4*)hbuf;
            *(ushort4*)&lds_wl[off] = *(const ushort4*)lbuf;
        }
        lds_csqp[q][k] = s;
    }
    __syncthreads();
    if (t < K_)
        lds_csq[t] = lds_csqp[0][t] + lds_csqp[1][t] + lds_csqp[2][t] + lds_csqp[3][t];

    // ---- MFMA main loop: acc[kt] (16x16 tiles) over 4 d-chunks x 3 split terms ----
    // A[m=lane&15][k=quad*8+j] = x[n][d][l0+wave*16+col] with d = dc*32+quad*8+j
    const float* xa = x + (size_t)n * D_ * L_ + l0 + wave * 16 + col;

    f32x4 acc[4];
#pragma unroll
    for (int kt = 0; kt < 4; ++kt) acc[kt] = (f32x4){0.f, 0.f, 0.f, 0.f};
    float xsq = 0.f;

#pragma unroll
    for (int dc = 0; dc < 4; ++dc) {
        const float* xp = xa + (size_t)(dc * 32 + quad * 8) * L_;
        float xv[8];
#pragma unroll
        for (int j = 0; j < 8; ++j) xv[j] = xp[(size_t)j * L_];

        __attribute__((aligned(16))) unsigned short ah[8], al[8];
#pragma unroll
        for (int j = 0; j < 8; ++j) {
            xsq = fmaf(xv[j], xv[j], xsq);
            unsigned short h = f2bf(xv[j]);
            ah[j] = h;
            al[j] = f2bf(xv[j] - bf2f(h));
        }
        bf16x8 afh = *(const bf16x8*)ah;
        bf16x8 afl = *(const bf16x8*)al;

        const int wb = dc * 32 + quad * 8;       // B[n=col][k=quad*8+j], W row-major
#pragma unroll
        for (int kt = 0; kt < 4; ++kt) {
            const int row = kt * 16 + col;
            bf16x8 bh = *(const bf16x8*)&lds_wh[row * WSTR + wb];
            bf16x8 bl = *(const bf16x8*)&lds_wl[row * WSTR + wb];
            acc[kt] = __builtin_amdgcn_mfma_f32_16x16x32_bf16(afh, bh, acc[kt], 0, 0, 0);
            acc[kt] = __builtin_amdgcn_mfma_f32_16x16x32_bf16(afl, bh, acc[kt], 0, 0, 0);
            acc[kt] = __builtin_amdgcn_mfma_f32_16x16x32_bf16(afh, bl, acc[kt], 0, 0, 0);
        }
    }

    // ---- ||x||^2: lane has 32 of 128 d's for l = l0+wave*16+col; butterfly over quads ----
    xsq += __shfl_xor(xsq, 16, 64);
    xsq += __shfl_xor(xsq, 32, 64);
    if (quad == 0) lds_xsq[wave * 16 + col] = xsq;

    __syncthreads();   // all W-hi ds_reads done; xsq written

    // ---- C tile -> LDS (reuse W-hi region), layout [k][l] stride 65 (conflict-free) ----
    // D layout: col(lane&15)=k free dim, row(quad*4+reg)=l free dim  [m89-verified]
#pragma unroll
    for (int kt = 0; kt < 4; ++kt) {
        const int kk = kt * 16 + col;
#pragma unroll
        for (int r = 0; r < 4; ++r) {
            const int ll = wave * 16 + quad * 4 + r;
            lds_c[kk * 65 + ll] = acc[kt][r];
        }
    }
    __syncthreads();

    // ---- fused epilogue, coalesced stores: kk = it*4+wave (uniform), ll = lane ----
    const float sc = scale[0];
    const float inv_s2 = 1.0f / (sc * sc);
    float* op = out + (size_t)n * K_ * L_ + l0;
#pragma unroll
    for (int it = 0; it < 16; ++it) {
        const int idx = it * 256 + t;
        const int kk = idx >> 6, ll = idx & 63;
        op[(size_t)kk * L_ + ll] =
            (lds_xsq[ll] + lds_csq[kk] - 2.0f * lds_c[kk * 65 + ll]) * inv_s2;
    }
}

extern "C" void kernel_launch(void* const* d_in, const int* in_sizes, int n_in,
                              void* d_out, int out_size, void* d_ws, size_t ws_size,
                              hipStream_t stream) {
    const float* x     = (const float*)d_in[0];
    const float* w     = (const float*)d_in[1];
    const float* scale = (const float*)d_in[2];
    float* out = (float*)d_out;

    dim3 grid(L_ / 64, N_);     // (49, 32): 1568 blocks, no tail (49*64 = 3136)
    enc_mfma_kernel<<<grid, 256, 0, stream>>>(x, w, scale, out);
}